// Round 1
// baseline (160.551 us; speedup 1.0000x reference)
//
#include <hip/hip_runtime.h>
#include <hip/hip_bf16.h>
#include <stdint.h>

// VQ-VAE vector quantizer forward, MI355X (gfx950).
// z: [32,256,32,32] fp32 (NCHW), E: [1024,256] fp32.
// scores(n,k) = 0.5*||e_k||^2 - <f_n, e_k>  (argmin-equivalent to full d2)
// dots via bf16 MFMA 16x16x32 (fp32 accum); losses/gather in exact fp32.

#define NB    32
#define ND    256
#define NHW   1024
#define NROW  32768   // NB*NHW
#define NK    1024

typedef short v8s __attribute__((ext_vector_type(8)));
typedef float v4f __attribute__((ext_vector_type(4)));

__device__ inline unsigned short f2bf(float f) {  // RNE fp32->bf16
    uint32_t u = __float_as_uint(f);
    uint32_t r = (u + 0x7fffu + ((u >> 16) & 1u)) >> 16;
    return (unsigned short)r;
}

// ---------------- Kernel 1: z (NCHW fp32) -> Abf[n][d] bf16, n=b*1024+hw ----
__global__ __launch_bounds__(256) void k_prep_a(const float* __restrict__ z,
                                                unsigned short* __restrict__ Abf) {
    __shared__ float t[32][33];           // +1 pad: conflict-free transpose
    int bid = blockIdx.x;
    int b  = bid >> 8;                    // 32
    int dt = (bid >> 5) & 7;              // 8 tiles of 32 d
    int ht = bid & 31;                    // 32 tiles of 32 hw
    int d0 = dt << 5, hw0 = ht << 5;
    int tx = threadIdx.x & 31, ty = threadIdx.x >> 5;   // tx: hw, ty: 8 rows
    const float* zb = z + ((size_t)b << 18);            // b*256*1024
#pragma unroll
    for (int i = 0; i < 4; i++) {
        int dl = ty + (i << 3);
        t[dl][tx] = zb[(size_t)(d0 + dl) * 1024 + hw0 + tx];
    }
    __syncthreads();
#pragma unroll
    for (int i = 0; i < 4; i++) {
        int hwl = ty + (i << 3);
        Abf[((size_t)(b * 1024 + hw0 + hwl)) * 256 + d0 + tx] = f2bf(t[tx][hwl]);
    }
}

// ---------------- Kernel 2: E -> Ebf bf16, normE2 fp32, zero accum ----------
__global__ __launch_bounds__(256) void k_prep_e(const float* __restrict__ E,
                                                unsigned short* __restrict__ Ebf,
                                                float* __restrict__ normE2,
                                                float* __restrict__ accum) {
    int k = blockIdx.x, tid = threadIdx.x;
    float v = E[(size_t)k * 256 + tid];
    Ebf[(size_t)k * 256 + tid] = f2bf(v);
    float s = v * v;
#pragma unroll
    for (int off = 1; off < 64; off <<= 1) s += __shfl_xor(s, off);
    __shared__ float w4[4];
    if ((tid & 63) == 0) w4[tid >> 6] = s;
    __syncthreads();
    if (tid == 0) {
        normE2[k] = w4[0] + w4[1] + w4[2] + w4[3];
        if (k == 0) accum[0] = 0.f;
    }
}

// ---------------- Kernel 3: fused MFMA GEMM + argmin ------------------------
// 256 blocks x 256 thr (4 waves). Block: rows R0..R0+127 (32/wave) vs all 1024
// codes. E-tile (16 codes x 256 d) double-buffered in LDS, bank-swizzled:
// unit u(c,dc,g) = dc*64 + g*16 + c holds Ebf[tile*16+c][dc*32+g*8 .. +8).
__global__ __launch_bounds__(256) void k_argmin(const unsigned short* __restrict__ Abf,
                                                const unsigned short* __restrict__ Ebf,
                                                const float* __restrict__ normE2,
                                                int* __restrict__ idxOut) {
    __shared__ v8s lds[2][512];           // 2 x 8 KB
    int tid = threadIdx.x;
    int lane = tid & 63, w = tid >> 6;
    int g = lane >> 4, m = lane & 15;
    int R0 = blockIdx.x << 7;

    // A fragments: 2 row-sets x 8 d-chunks, 16B each (64 VGPRs)
    v8s a[2][8];
    {
        const v8s* Ap = (const v8s*)Abf;  // v8s index = elem/8 = row*32 + dc*4 + g
        int rbase = R0 + w * 32;
#pragma unroll
        for (int s = 0; s < 2; s++) {
            int row = rbase + s * 16 + m;
#pragma unroll
            for (int dc = 0; dc < 8; dc++)
                a[s][dc] = Ap[row * 32 + dc * 4 + g];
        }
    }

    // staging: thread stages units u0=tid, u1=tid+256
    // elem offset within tile: (u&15)*256 + (u>>6)*32 + ((u>>4)&3)*8
    int go  = (tid & 15) * 256 + (tid >> 6) * 32 + ((tid >> 4) & 3) * 8;
    int gv0 = go >> 3, gv1 = gv0 + 16;    // v8s offsets (u1 adds 4 to u>>6)
    const v8s* Ep = (const v8s*)Ebf;

    float best[2][4];
    int   bidx[2][4];
#pragma unroll
    for (int s = 0; s < 2; s++)
#pragma unroll
        for (int r = 0; r < 4; r++) { best[s][r] = 3.4e38f; bidx[s][r] = 0; }

    v8s st0 = Ep[gv0], st1 = Ep[gv1];     // prologue: tile 0
    lds[0][tid] = st0;
    lds[0][tid + 256] = st1;

    for (int ct = 0; ct < 64; ct++) {
        __syncthreads();
        int cur = ct & 1;
        if (ct < 63) {                    // prefetch next tile into regs
            st0 = Ep[(ct + 1) * 512 + gv0];
            st1 = Ep[(ct + 1) * 512 + gv1];
        }
        v4f acc0 = {0.f, 0.f, 0.f, 0.f}, acc1 = {0.f, 0.f, 0.f, 0.f};
#pragma unroll
        for (int dc = 0; dc < 8; dc++) {
            v8s bf = lds[cur][dc * 64 + g * 16 + m];
            acc0 = __builtin_amdgcn_mfma_f32_16x16x32_bf16(a[0][dc], bf, acc0, 0, 0, 0);
            acc1 = __builtin_amdgcn_mfma_f32_16x16x32_bf16(a[1][dc], bf, acc1, 0, 0, 0);
        }
        int code = (ct << 4) + m;         // C/D: col = lane&15
        float nE = 0.5f * normE2[code];
#pragma unroll
        for (int r = 0; r < 4; r++) {
            float s0 = nE - acc0[r];
            if (s0 < best[0][r]) { best[0][r] = s0; bidx[0][r] = code; }
            float s1 = nE - acc1[r];
            if (s1 < best[1][r]) { best[1][r] = s1; bidx[1][r] = code; }
        }
        if (ct < 63) {                    // stage next tile (other buffer)
            lds[cur ^ 1][tid] = st0;
            lds[cur ^ 1][tid + 256] = st1;
        }
    }

    // reduce across the 16 code-columns (lanes sharing g hold same rows)
#pragma unroll
    for (int s = 0; s < 2; s++)
#pragma unroll
        for (int r = 0; r < 4; r++) {
            float bs = best[s][r]; int bi = bidx[s][r];
#pragma unroll
            for (int off = 1; off < 16; off <<= 1) {
                float os = __shfl_xor(bs, off);
                int   oi = __shfl_xor(bi, off);
                if (os < bs || (os == bs && oi < bi)) { bs = os; bi = oi; }
            }
            if (m == 0)                   // C/D row = g*4 + r
                idxOut[R0 + w * 32 + s * 16 + g * 4 + r] = bi;
        }
}

// ---------------- Kernel 4: gather + NCHW write + loss reduction ------------
__global__ __launch_bounds__(256) void k_out(const float* __restrict__ z,
                                             const float* __restrict__ E,
                                             const int* __restrict__ idx,
                                             float* __restrict__ out,
                                             float* __restrict__ accum) {
    __shared__ float et[32][257];         // 32 gathered code rows, padded
    __shared__ int   kk[32];
    __shared__ float w4[4];
    int bid = blockIdx.x;
    int b = bid >> 5, ht = bid & 31;
    int hw0 = ht << 5;
    int tid = threadIdx.x;
    if (tid < 32) kk[tid] = idx[b * 1024 + hw0 + tid];
    __syncthreads();
    for (int r = 0; r < 32; r++)          // coalesced 1KB row gathers
        et[r][tid] = E[(size_t)kk[r] * 256 + tid];
    __syncthreads();

    int c = tid & 31, dt = tid >> 5;      // c: hw within tile, dt: 0..7
    const float* zb = z + ((size_t)b << 18);
    float* ob = out + ((size_t)b << 18);
    float lsum = 0.f;
#pragma unroll
    for (int i = 0; i < 32; i++) {
        int d = dt + (i << 3);
        float ev = et[c][d];              // banks (c+d)%32: conflict-free
        size_t o = (size_t)d * 1024 + hw0 + c;
        float zv = zb[o];
        ob[o] = ev;                       // z_st forward value == z_quant
        float df = ev - zv;
        lsum += df * df;
    }
#pragma unroll
    for (int off = 1; off < 64; off <<= 1) lsum += __shfl_xor(lsum, off);
    if ((tid & 63) == 0) w4[tid >> 6] = lsum;
    __syncthreads();
    if (tid == 0) atomicAdd(accum, w4[0] + w4[1] + w4[2] + w4[3]);
}

// ---------------- Kernel 5: scalar outputs ----------------------------------
__global__ void k_loss(const float* __restrict__ accum, float* __restrict__ out) {
    if (threadIdx.x == 0) {
        float s = accum[0] * (1.0f / 8388608.0f);   // mean over N*D
        out[8388608] = 1.25f * s;                   // loss = cb + 0.25*commit
        out[8388609] = s;                           // codebook_loss
        out[8388610] = s;                           // commitment_loss
    }
}

extern "C" void kernel_launch(void* const* d_in, const int* in_sizes, int n_in,
                              void* d_out, int out_size, void* d_ws, size_t ws_size,
                              hipStream_t stream) {
    const float* z = (const float*)d_in[0];
    const float* E = (const float*)d_in[1];
    char* ws = (char*)d_ws;
    unsigned short* Abf   = (unsigned short*)(ws);               // 16,777,216 B
    unsigned short* Ebf   = (unsigned short*)(ws + 16777216);    //    524,288 B
    float*          nrmE  = (float*)(ws + 17301504);             //      4,096 B
    int*            idx   = (int*)(ws + 17305600);               //    131,072 B
    float*          accum = (float*)(ws + 17436672);             //          4 B
    float* out = (float*)d_out;

    hipLaunchKernelGGL(k_prep_a, dim3(8192), dim3(256), 0, stream, z, Abf);
    hipLaunchKernelGGL(k_prep_e, dim3(1024), dim3(256), 0, stream, E, Ebf, nrmE, accum);
    hipLaunchKernelGGL(k_argmin, dim3(256), dim3(256), 0, stream, Abf, Ebf, nrmE, idx);
    hipLaunchKernelGGL(k_out,    dim3(1024), dim3(256), 0, stream, z, E, idx, out, accum);
    hipLaunchKernelGGL(k_loss,   dim3(1),    dim3(64),  0, stream, accum, out);
}

// Round 2
// 141.129 us; speedup vs baseline: 1.1376x; 1.1376x over previous
//
#include <hip/hip_runtime.h>
#include <hip/hip_bf16.h>
#include <stdint.h>

// VQ-VAE vector quantizer forward, MI355X (gfx950).
// z: [32,256,32,32] fp32 (NCHW), E: [1024,256] fp32.
// score(n,k) = 0.5*||e_k||^2 - <f_n,e_k>  (argmin-equivalent to d2)
// dots via bf16 MFMA 16x16x32 fp32-accum; losses/gather exact fp32.

typedef short v8s __attribute__((ext_vector_type(8)));
typedef float v4f __attribute__((ext_vector_type(4)));

__device__ inline unsigned short f2bf(float f) {  // RNE fp32->bf16
    uint32_t u = __float_as_uint(f);
    return (unsigned short)((u + 0x7fffu + ((u >> 16) & 1u)) >> 16);
}

// ---- Kernel 1: z (NCHW fp32) -> Abf[n][d] bf16, register-only transpose ----
// grid 512 = 32 b x 16 hw-tiles(64); block 512. Thread: 8 d x 4 hw micro-tile.
__global__ __launch_bounds__(512) void k_prep_a(const float* __restrict__ z,
                                                unsigned short* __restrict__ Abf) {
    int tid = threadIdx.x;
    int b = blockIdx.x >> 4, hw0 = (blockIdx.x & 15) << 6;
    int t15 = tid & 15, dblk = tid >> 4;            // hwq = 4*t15, d0 = 8*dblk
    const float* zp = z + ((size_t)b << 18) + (size_t)(dblk << 3) * 1024 + hw0 + (t15 << 2);
    float4 L[8];
#pragma unroll
    for (int j = 0; j < 8; j++)                     // 16 lanes x 16B = 256B contiguous
        L[j] = *(const float4*)(zp + (size_t)j * 1024);
    const float* Lf = (const float*)L;
    v8s* Aout = (v8s*)Abf + ((size_t)(b * 1024 + hw0 + (t15 << 2))) * 32 + dblk;
#pragma unroll
    for (int c = 0; c < 4; c++) {                   // in-register transpose
        union { v8s v; unsigned short s[8]; } u;
#pragma unroll
        for (int j = 0; j < 8; j++) u.s[j] = f2bf(Lf[j * 4 + c]);
        Aout[(size_t)c * 32] = u.v;
    }
}

// ---- Kernel 2: E -> Ebf bf16, nE = 0.5*||e||^2, zero loss accumulator ------
__global__ __launch_bounds__(256) void k_prep_e(const float* __restrict__ E,
                                                unsigned short* __restrict__ Ebf,
                                                float* __restrict__ nE,
                                                float* __restrict__ accum) {
    int k = blockIdx.x, tid = threadIdx.x;
    float v = E[(size_t)k * 256 + tid];
    Ebf[(size_t)k * 256 + tid] = f2bf(v);
    float s = v * v;
#pragma unroll
    for (int off = 1; off < 64; off <<= 1) s += __shfl_xor(s, off);
    __shared__ float w4[4];
    if ((tid & 63) == 0) w4[tid >> 6] = s;
    __syncthreads();
    if (tid == 0) {
        nE[k] = 0.5f * (w4[0] + w4[1] + w4[2] + w4[3]);
        if (k == 0) accum[0] = 0.f;
    }
}

// ---- Kernel 3: fused MFMA GEMM + per-split argmin --------------------------
// grid 1024 = 128 row-groups(256 rows) x 8 code-splits(128 codes); block 512.
// Whole B panel (128x256 bf16 = 64KB) in LDS, staged once; main loop has NO
// barriers and NO global loads. Winner packed (sortfloat<<32|idx) -> cand.
__global__ __launch_bounds__(512, 4) void k_argmin(
        const unsigned short* __restrict__ Abf,
        const unsigned short* __restrict__ Ebf,
        const float* __restrict__ nE,
        unsigned long long* __restrict__ cand) {
    __shared__ v8s B[4096];                    // exactly 64 KB
    int tid = threadIdx.x;
    int lane = tid & 63, w = tid >> 6;
    int g = lane >> 4, m = lane & 15;          // MFMA A/B lane coords
    int split = blockIdx.x & 7;
    int R0 = (blockIdx.x >> 3) << 8;
    int C0 = split << 7;

    // stage B: unit u = ct*512 + dc*64 + g*16 + m  (b128 reads 2-way free)
    const v8s* Ep = (const v8s*)Ebf;
#pragma unroll
    for (int k = 0; k < 8; k++) {
        int u = tid + (k << 9);
        int um = u & 15, ug = (u >> 4) & 3, udc = (u >> 6) & 7, uct = u >> 9;
        B[u] = Ep[(size_t)(C0 + uct * 16 + um) * 32 + udc * 4 + ug];
    }
    float ne[8];                               // per-lane code norms in regs
#pragma unroll
    for (int ct = 0; ct < 8; ct++) ne[ct] = nE[C0 + ct * 16 + m];

    v8s a[2][8];                               // A frags: 32 rows/wave
    const v8s* Ap = (const v8s*)Abf;
    int rbase = R0 + w * 32;
#pragma unroll
    for (int s = 0; s < 2; s++) {
        int row = rbase + s * 16 + m;
#pragma unroll
        for (int dc = 0; dc < 8; dc++)
            a[s][dc] = Ap[(size_t)row * 32 + dc * 4 + g];
    }
    __syncthreads();                           // the only barrier

    float best[2][4]; int bidx[2][4];
#pragma unroll
    for (int s = 0; s < 2; s++)
#pragma unroll
        for (int r = 0; r < 4; r++) { best[s][r] = 3.4e38f; bidx[s][r] = 0; }

#pragma unroll 1
    for (int ct = 0; ct < 8; ct++) {
        v4f acc0 = {0.f, 0.f, 0.f, 0.f}, acc1 = {0.f, 0.f, 0.f, 0.f};
#pragma unroll
        for (int dc = 0; dc < 8; dc++) {
            v8s bf = B[ct * 512 + dc * 64 + g * 16 + m];
            acc0 = __builtin_amdgcn_mfma_f32_16x16x32_bf16(a[0][dc], bf, acc0, 0, 0, 0);
            acc1 = __builtin_amdgcn_mfma_f32_16x16x32_bf16(a[1][dc], bf, acc1, 0, 0, 0);
        }
        int code = C0 + (ct << 4) + m;         // C/D col = lane&15
        float nv = ne[ct];
#pragma unroll
        for (int r = 0; r < 4; r++) {
            float s0 = nv - acc0[r];
            if (s0 < best[0][r]) { best[0][r] = s0; bidx[0][r] = code; }
            float s1 = nv - acc1[r];
            if (s1 < best[1][r]) { best[1][r] = s1; bidx[1][r] = code; }
        }
    }

    // reduce over the 16 code columns; pack for global min with idx tiebreak
#pragma unroll
    for (int s = 0; s < 2; s++)
#pragma unroll
        for (int r = 0; r < 4; r++) {
            uint32_t sb = __float_as_uint(best[s][r]);
            sb = (sb & 0x80000000u) ? ~sb : (sb | 0x80000000u);
            unsigned long long pk = ((unsigned long long)sb << 32) | (uint32_t)bidx[s][r];
#pragma unroll
            for (int off = 1; off < 16; off <<= 1) {
                unsigned long long o = __shfl_xor(pk, off);
                if (o < pk) pk = o;
            }
            if (m == 0)                        // C/D row = g*4 + r
                cand[(size_t)split * 32768 + R0 + w * 32 + s * 16 + g * 4 + r] = pk;
        }
}

// ---- Kernel 4: combine splits + gather + NCHW write + loss reduction -------
__global__ __launch_bounds__(256) void k_out(const float* __restrict__ z,
                                             const float* __restrict__ E,
                                             const unsigned long long* __restrict__ cand,
                                             float* __restrict__ out,
                                             float* __restrict__ accum) {
    __shared__ float et[256][33];              // [d][hw] padded: <=2-way banks
    __shared__ int   kk[32];
    __shared__ float w4[4];
    int bid = blockIdx.x;
    int b = bid >> 5, hw0 = (bid & 31) << 5;
    int tid = threadIdx.x;
    if (tid < 32) {
        int n = b * 1024 + hw0 + tid;
        unsigned long long bv = cand[n];
#pragma unroll
        for (int s = 1; s < 8; s++) {
            unsigned long long v = cand[(size_t)s * 32768 + n];
            if (v < bv) bv = v;
        }
        kk[tid] = (int)(bv & 0xffffffffu);
    }
    __syncthreads();
    for (int r = 0; r < 32; r++)               // coalesced 1KB row gathers
        et[tid][r] = E[(size_t)kk[r] * 256 + tid];
    __syncthreads();

    int c4 = (tid & 7) << 2, dt = tid >> 3;
    const float* zb = z + ((size_t)b << 18);
    float* ob = out + ((size_t)b << 18);
    float lsum = 0.f;
#pragma unroll
    for (int i = 0; i < 8; i++) {
        int d = dt + (i << 5);
        size_t o = (size_t)d * 1024 + hw0 + c4;
        const float4 zv = *(const float4*)(zb + o);
        float4 ev;
        ev.x = et[d][c4]; ev.y = et[d][c4 + 1]; ev.z = et[d][c4 + 2]; ev.w = et[d][c4 + 3];
        *(float4*)(ob + o) = ev;               // z_st forward value == z_quant
        float dx = ev.x - zv.x, dy = ev.y - zv.y, dz2 = ev.z - zv.z, dw = ev.w - zv.w;
        lsum += dx * dx + dy * dy + dz2 * dz2 + dw * dw;
    }
#pragma unroll
    for (int off = 1; off < 64; off <<= 1) lsum += __shfl_xor(lsum, off);
    if ((tid & 63) == 0) w4[tid >> 6] = lsum;
    __syncthreads();
    if (tid == 0) atomicAdd(accum, w4[0] + w4[1] + w4[2] + w4[3]);
}

// ---- Kernel 5: scalar outputs ----------------------------------------------
__global__ void k_loss(const float* __restrict__ accum, float* __restrict__ out) {
    if (threadIdx.x == 0) {
        float s = accum[0] * (1.0f / 8388608.0f);
        out[8388608] = 1.25f * s;
        out[8388609] = s;
        out[8388610] = s;
    }
}

extern "C" void kernel_launch(void* const* d_in, const int* in_sizes, int n_in,
                              void* d_out, int out_size, void* d_ws, size_t ws_size,
                              hipStream_t stream) {
    const float* z = (const float*)d_in[0];
    const float* E = (const float*)d_in[1];
    char* ws = (char*)d_ws;
    unsigned short*     Abf   = (unsigned short*)(ws);               // 16,777,216 B
    unsigned short*     Ebf   = (unsigned short*)(ws + 16777216);    //    524,288 B
    float*              nE    = (float*)(ws + 17301504);             //      4,096 B
    unsigned long long* cand  = (unsigned long long*)(ws + 17305600);// 2,097,152 B
    float*              accum = (float*)(ws + 19402752);             //          4 B
    float* out = (float*)d_out;

    hipLaunchKernelGGL(k_prep_a, dim3(512),  dim3(512), 0, stream, z, Abf);
    hipLaunchKernelGGL(k_prep_e, dim3(1024), dim3(256), 0, stream, E, Ebf, nE, accum);
    hipLaunchKernelGGL(k_argmin, dim3(1024), dim3(512), 0, stream, Abf, Ebf, nE, cand);
    hipLaunchKernelGGL(k_out,    dim3(1024), dim3(256), 0, stream, z, E, cand, out, accum);
    hipLaunchKernelGGL(k_loss,   dim3(1),    dim3(64),  0, stream, accum, out);
}

// Round 3
// 141.023 us; speedup vs baseline: 1.1385x; 1.0007x over previous
//
#include <hip/hip_runtime.h>
#include <hip/hip_bf16.h>
#include <stdint.h>

// VQ-VAE vector quantizer forward, MI355X (gfx950).
// z: [32,256,32,32] fp32 (NCHW), E: [1024,256] fp32.
// score(n,k) = 0.5*||e_k||^2 - <f_n,e_k>  (argmin-equivalent to d2)
// dots via bf16 MFMA 16x16x32 fp32-accum; losses/gather exact fp32.
//
// Structure: k_prep_a (z->Abf bf16) ; k_prep_e (E->Ebf, norms, accum=0) ;
// k_main (fused GEMM+argmin+gather+NCHW out+loss, B double-buffered via
// global_load_lds) ; k_loss (scalars).

typedef short v8s __attribute__((ext_vector_type(8)));
typedef float v4f __attribute__((ext_vector_type(4)));

__device__ inline unsigned short f2bf(float f) {  // RNE fp32->bf16
    uint32_t u = __float_as_uint(f);
    return (unsigned short)((u + 0x7fffu + ((u >> 16) & 1u)) >> 16);
}

// ---- Kernel 1: z (NCHW fp32) -> Abf[n][d] bf16, register-only transpose ----
__global__ __launch_bounds__(512) void k_prep_a(const float* __restrict__ z,
                                                unsigned short* __restrict__ Abf) {
    int tid = threadIdx.x;
    int b = blockIdx.x >> 4, hw0 = (blockIdx.x & 15) << 6;
    int t15 = tid & 15, dblk = tid >> 4;            // hwq = 4*t15, d0 = 8*dblk
    const float* zp = z + ((size_t)b << 18) + (size_t)(dblk << 3) * 1024 + hw0 + (t15 << 2);
    float4 L[8];
#pragma unroll
    for (int j = 0; j < 8; j++)                     // 16 lanes x 16B contiguous
        L[j] = *(const float4*)(zp + (size_t)j * 1024);
    const float* Lf = (const float*)L;
    v8s* Aout = (v8s*)Abf + ((size_t)(b * 1024 + hw0 + (t15 << 2))) * 32 + dblk;
#pragma unroll
    for (int c = 0; c < 4; c++) {                   // in-register transpose
        union { v8s v; unsigned short s[8]; } u;
#pragma unroll
        for (int j = 0; j < 8; j++) u.s[j] = f2bf(Lf[j * 4 + c]);
        Aout[(size_t)c * 32] = u.v;
    }
}

// ---- Kernel 2: E -> Ebf bf16, nE = 0.5*||e||^2, zero loss accumulator ------
__global__ __launch_bounds__(256) void k_prep_e(const float* __restrict__ E,
                                                unsigned short* __restrict__ Ebf,
                                                float* __restrict__ nE,
                                                float* __restrict__ accum) {
    int k = blockIdx.x, tid = threadIdx.x;
    float v = E[(size_t)k * 256 + tid];
    Ebf[(size_t)k * 256 + tid] = f2bf(v);
    float s = v * v;
#pragma unroll
    for (int off = 1; off < 64; off <<= 1) s += __shfl_xor(s, off);
    __shared__ float w4[4];
    if ((tid & 63) == 0) w4[tid >> 6] = s;
    __syncthreads();
    if (tid == 0) {
        nE[k] = 0.5f * (w4[0] + w4[1] + w4[2] + w4[3]);
        if (k == 0) accum[0] = 0.f;
    }
}

// ---- Kernel 3: fused GEMM+argmin+gather+output+loss -------------------------
// 512 blocks x 256 thr (4 waves). Block owns 64 rows (16/wave). 16 chunks of
// 64 codes; B chunk (32KB) double-buffered in LDS via global_load_lds w=16.
// LDS unit u = ctile*512 + dc*64 + g*16 + m  (ds_read_b128 conflict-free).
__global__ __launch_bounds__(256, 2) void k_main(
        const unsigned short* __restrict__ Abf,
        const unsigned short* __restrict__ Ebf,
        const float* __restrict__ nE,
        const float* __restrict__ z,
        const float* __restrict__ E,
        float* __restrict__ out,
        float* __restrict__ accum) {
    __shared__ union {
        v8s   B[2][2048];         // 2 x 32 KB staging
        float Eg[32][260];        // epilogue gather tile (33,280 B)
    } S;
    __shared__ int   idxLds[64];
    __shared__ float w4[4];

    int tid = threadIdx.x;
    int lane = tid & 63, w = tid >> 6;
    int g = lane >> 4, m = lane & 15;          // MFMA lane coords
    int R0 = blockIdx.x << 6;                  // 64 rows/block
    int b = R0 >> 10, hw0 = R0 & 1023;

    // A fragments: 16 rows/wave, read exactly once from global
    v8s a[8];
    {
        const v8s* Ap = (const v8s*)Abf;
        int row = R0 + w * 16 + m;
#pragma unroll
        for (int dc = 0; dc < 8; dc++)
            a[dc] = Ap[(size_t)row * 32 + dc * 4 + g];
    }

    const v8s* Ep = (const v8s*)Ebf;
    // async stage: per wave 8 issues; unit u = (w*8+k)*64 + lane
#define STAGE(ch, bufSel)                                                     \
    {                                                                         \
        _Pragma("unroll")                                                     \
        for (int k = 0; k < 8; k++) {                                         \
            int u  = (((w << 3) + k) << 6) + lane;                            \
            int um = u & 15, ug = (u >> 4) & 3;                               \
            int udc = (u >> 6) & 7, uct = (u >> 9) & 3;                       \
            const v8s* gp = Ep + ((size_t)((ch) * 64 + uct * 16 + um) * 32    \
                                  + udc * 4 + ug);                            \
            __builtin_amdgcn_global_load_lds(                                 \
                (const __attribute__((address_space(1))) void*)gp,            \
                (__attribute__((address_space(3))) void*)                     \
                    &S.B[bufSel][((w << 3) + k) << 6],                        \
                16, 0, 0);                                                    \
        }                                                                     \
    }

    float best[4]; int bidx[4];
#pragma unroll
    for (int r = 0; r < 4; r++) { best[r] = 3.4e38f; bidx[r] = 0; }

    STAGE(0, 0);
#pragma unroll 1
    for (int ct = 0; ct < 16; ct++) {
        int cur = ct & 1;
        __syncthreads();                       // chunk ct resident; prev compute done
        if (ct < 15) STAGE(ct + 1, cur ^ 1);   // prefetch overlaps compute below
        float ne4[4];
#pragma unroll
        for (int t = 0; t < 4; t++) ne4[t] = nE[ct * 64 + t * 16 + m];
#pragma unroll
        for (int t = 0; t < 4; t++) {
            v4f acc = {0.f, 0.f, 0.f, 0.f};
#pragma unroll
            for (int dc = 0; dc < 8; dc++) {
                v8s bf = S.B[cur][t * 512 + dc * 64 + g * 16 + m];
                acc = __builtin_amdgcn_mfma_f32_16x16x32_bf16(a[dc], bf, acc, 0, 0, 0);
            }
            int code = ct * 64 + t * 16 + m;   // C/D col = lane&15
#pragma unroll
            for (int r = 0; r < 4; r++) {
                float s = ne4[t] - acc[r];
                if (s < best[r]) { best[r] = s; bidx[r] = code; }
            }
        }
    }

    // reduce winners over the 16 code columns; tiebreak = lowest index
#pragma unroll
    for (int r = 0; r < 4; r++) {
        uint32_t sb = __float_as_uint(best[r]);
        sb = (sb & 0x80000000u) ? ~sb : (sb | 0x80000000u);
        unsigned long long pk = ((unsigned long long)sb << 32) | (uint32_t)bidx[r];
#pragma unroll
        for (int off = 1; off < 16; off <<= 1) {
            unsigned long long o = __shfl_xor(pk, off);
            if (o < pk) pk = o;
        }
        if (m == 0)                            // C/D row = g*4 + r
            idxLds[w * 16 + g * 4 + r] = (int)(pk & 0xffffffffu);
    }
    __syncthreads();

    // epilogue: 2 halves of 32 rows; gather E fp32 -> LDS, write NCHW, loss
    float lsum = 0.f;
    const float* zb = z + ((size_t)b << 18);
    float* ob = out + ((size_t)b << 18);
#pragma unroll 1
    for (int h = 0; h < 2; h++) {
        {
            int j2 = tid >> 3, dq = tid & 7;   // 32 rows x 8 float4-lanes
            int k = idxLds[h * 32 + j2];
            const float* ep = E + (size_t)k * 256 + (dq << 2);
#pragma unroll
            for (int i = 0; i < 8; i++)
                *(float4*)&S.Eg[j2][(dq << 2) + i * 32] =
                    *(const float4*)(ep + i * 32);
        }
        __syncthreads();
        {
            int jj = (tid & 7) << 2, dt = tid >> 3;   // 4 hw x 32 d-bases
#pragma unroll
            for (int i = 0; i < 8; i++) {
                int d = dt + (i << 5);
                size_t o = (size_t)d * 1024 + hw0 + (h << 5) + jj;
                float4 zv = *(const float4*)(zb + o);
                float4 ev;
                ev.x = S.Eg[jj + 0][d]; ev.y = S.Eg[jj + 1][d];
                ev.z = S.Eg[jj + 2][d]; ev.w = S.Eg[jj + 3][d];
                *(float4*)(ob + o) = ev;       // z_st forward == z_quant
                float dx = ev.x - zv.x, dy = ev.y - zv.y;
                float dz2 = ev.z - zv.z, dw = ev.w - zv.w;
                lsum += dx * dx + dy * dy + dz2 * dz2 + dw * dw;
            }
        }
        __syncthreads();                        // Eg reused next half
    }
#pragma unroll
    for (int off = 1; off < 64; off <<= 1) lsum += __shfl_xor(lsum, off);
    if ((tid & 63) == 0) w4[tid >> 6] = lsum;
    __syncthreads();
    if (tid == 0) atomicAdd(accum, w4[0] + w4[1] + w4[2] + w4[3]);
#undef STAGE
}

// ---- Kernel 4: scalar outputs ----------------------------------------------
__global__ void k_loss(const float* __restrict__ accum, float* __restrict__ out) {
    if (threadIdx.x == 0) {
        float s = accum[0] * (1.0f / 8388608.0f);
        out[8388608] = 1.25f * s;
        out[8388609] = s;
        out[8388610] = s;
    }
}

extern "C" void kernel_launch(void* const* d_in, const int* in_sizes, int n_in,
                              void* d_out, int out_size, void* d_ws, size_t ws_size,
                              hipStream_t stream) {
    const float* z = (const float*)d_in[0];
    const float* E = (const float*)d_in[1];
    char* ws = (char*)d_ws;
    unsigned short* Abf   = (unsigned short*)(ws);               // 16,777,216 B
    unsigned short* Ebf   = (unsigned short*)(ws + 16777216);    //    524,288 B
    float*          nE    = (float*)(ws + 17301504);             //      4,096 B
    float*          accum = (float*)(ws + 17305600);             //          4 B
    float* out = (float*)d_out;

    hipLaunchKernelGGL(k_prep_e, dim3(1024), dim3(256), 0, stream, E, Ebf, nE, accum);
    hipLaunchKernelGGL(k_prep_a, dim3(512),  dim3(512), 0, stream, z, Abf);
    hipLaunchKernelGGL(k_main,   dim3(512),  dim3(256), 0, stream,
                       Abf, Ebf, nE, z, E, out, accum);
    hipLaunchKernelGGL(k_loss,   dim3(1),    dim3(64),  0, stream, accum, out);
}

// Round 4
// 131.119 us; speedup vs baseline: 1.2245x; 1.0755x over previous
//
#include <hip/hip_runtime.h>
#include <hip/hip_bf16.h>
#include <stdint.h>

// VQ-VAE vector quantizer forward, MI355X (gfx950).
// z: [32,256,32,32] fp32 (NCHW), E: [1024,256] fp32.
// score(n,k) = 0.5*||e_k||^2 - <f_n,e_k>  (argmin-equivalent to d2)
// dots via bf16 MFMA 16x16x32 fp32-accum; losses/gather exact fp32.
//
// k_main: grid 256 x 256thr (4 waves). 128 rows/block, 32 rows/wave with
// A-reuse x2 (halves LDS b128 pressure — the R3 bottleneck). B staged via
// global_load_lds from PRE-SWIZZLED Ebf (contiguous 1KB/instr), chunks of
// 64 codes double-buffered. nE lives in LDS (no global loads in main loop).

typedef short v8s __attribute__((ext_vector_type(8)));
typedef float v4f __attribute__((ext_vector_type(4)));

__device__ inline unsigned short f2bf(float f) {  // RNE fp32->bf16
    uint32_t u = __float_as_uint(f);
    return (unsigned short)((u + 0x7fffu + ((u >> 16) & 1u)) >> 16);
}

// ---- Kernel 1: z (NCHW fp32) -> Abf[n][d] bf16, register-only transpose ----
__global__ __launch_bounds__(512) void k_prep_a(const float* __restrict__ z,
                                                unsigned short* __restrict__ Abf) {
    int tid = threadIdx.x;
    int b = blockIdx.x >> 4, hw0 = (blockIdx.x & 15) << 6;
    int t15 = tid & 15, dblk = tid >> 4;            // hwq = 4*t15, d0 = 8*dblk
    const float* zp = z + ((size_t)b << 18) + (size_t)(dblk << 3) * 1024 + hw0 + (t15 << 2);
    float4 L[8];
#pragma unroll
    for (int j = 0; j < 8; j++)
        L[j] = *(const float4*)(zp + (size_t)j * 1024);
    const float* Lf = (const float*)L;
    v8s* Aout = (v8s*)Abf + ((size_t)(b * 1024 + hw0 + (t15 << 2))) * 32 + dblk;
#pragma unroll
    for (int c = 0; c < 4; c++) {
        union { v8s v; unsigned short s[8]; } u;
#pragma unroll
        for (int j = 0; j < 8; j++) u.s[j] = f2bf(Lf[j * 4 + c]);
        Aout[(size_t)c * 32] = u.v;
    }
}

// ---- Kernel 2: E -> SWIZZLED Ebf bf16 + nE + accum=0 -----------------------
// Block q handles codes q*16..q*16+15. Output unit for (k, dc, g):
// U = (k>>4)*512 + dc*64 + g*16 + (k&15), holding elems d = dc*32+g*8 .. +8.
// Consecutive tid -> consecutive U: coalesced 16B stores.
__global__ __launch_bounds__(256) void k_prep_e(const float* __restrict__ E,
                                                v8s* __restrict__ Esw,
                                                float* __restrict__ nE,
                                                float* __restrict__ accum) {
    __shared__ float Ef[16][264];
    int q = blockIdx.x, tid = threadIdx.x;
    const float4* Ein = (const float4*)(E + ((size_t)q << 12));
#pragma unroll
    for (int i = 0; i < 4; i++) {
        int f4 = i * 256 + tid;                 // 1024 float4 = 16 rows x 256
        int row = f4 >> 6, c4 = (f4 & 63) << 2;
        *(float4*)&Ef[row][c4] = Ein[f4];
    }
    __syncthreads();
    {   // norms: code c = tid>>4, 16 lanes stride-16 partial sums
        int c = tid >> 4, l = tid & 15;
        float s = 0.f;
#pragma unroll
        for (int j = 0; j < 16; j++) { float v = Ef[c][l + 16 * j]; s += v * v; }
#pragma unroll
        for (int off = 1; off < 16; off <<= 1) s += __shfl_xor(s, off);
        if (l == 0) nE[q * 16 + c] = 0.5f * s;
    }
#pragma unroll
    for (int i = 0; i < 2; i++) {               // units U = q*512 + u'
        int u = tid + i * 256;
        int um = u & 15, ug = (u >> 4) & 3, udc = (u >> 6) & 7;
        int d0 = udc * 32 + ug * 8;
        union { v8s v; unsigned short s[8]; } pk;
#pragma unroll
        for (int e = 0; e < 8; e++) pk.s[e] = f2bf(Ef[um][d0 + e]);
        Esw[((size_t)q << 9) + u] = pk.v;
    }
    if (q == 0 && tid == 0) accum[0] = 0.f;
}

// ---- Kernel 3: fused GEMM+argmin+gather+output+loss -------------------------
__global__ __launch_bounds__(256) void k_main(
        const unsigned short* __restrict__ Abf,
        const v8s* __restrict__ Esw,
        const float* __restrict__ nE,
        const float* __restrict__ z,
        const float* __restrict__ E,
        float* __restrict__ out,
        float* __restrict__ accum) {
    __shared__ union {
        v8s   B[2][2048];          // 2 x 32 KB double-buffer
        float Eg[32 * 260];        // epilogue gather tile (33,280 B)
    } S;
    __shared__ float nEl[1024];
    __shared__ int   idxLds[128];
    __shared__ float w4[4];

    int tid = threadIdx.x;
    int lane = tid & 63, w = tid >> 6;
    int g = lane >> 4, m = lane & 15;          // MFMA lane coords
    int R0 = blockIdx.x << 7;                  // 128 rows/block
    int b = R0 >> 10, hw0 = R0 & 1023;

#pragma unroll
    for (int i = 0; i < 4; i++) nEl[tid + i * 256] = nE[tid + i * 256];

    // A frags: 32 rows/wave (2 row-sets), read once
    v8s a[2][8];
    {
        const v8s* Ap = (const v8s*)Abf;
#pragma unroll
        for (int s = 0; s < 2; s++) {
            int row = R0 + w * 32 + s * 16 + m;
#pragma unroll
            for (int dc = 0; dc < 8; dc++)
                a[s][dc] = Ap[(size_t)row * 32 + dc * 4 + g];
        }
    }

    // contiguous staging: chunk ch = 2048 v8s; thread stages u = j*256+tid
#define STAGE(ch, buf)                                                        \
    {                                                                         \
        _Pragma("unroll")                                                     \
        for (int j = 0; j < 8; j++) {                                         \
            __builtin_amdgcn_global_load_lds(                                 \
                (const __attribute__((address_space(1))) void*)               \
                    (Esw + ((size_t)(ch) << 11) + (j << 8) + tid),            \
                (__attribute__((address_space(3))) void*)                     \
                    &S.B[buf][(j << 8) + (w << 6)],                           \
                16, 0, 0);                                                    \
        }                                                                     \
    }

    float best[2][4]; int bidx[2][4];
#pragma unroll
    for (int s = 0; s < 2; s++)
#pragma unroll
        for (int r = 0; r < 4; r++) { best[s][r] = 3.4e38f; bidx[s][r] = 0; }

    STAGE(0, 0);
#pragma unroll 1
    for (int ct = 0; ct < 16; ct++) {
        int cur = ct & 1;
        __syncthreads();                       // chunk ct resident
        if (ct < 15) STAGE(ct + 1, cur ^ 1);
        float ne[4];
#pragma unroll
        for (int t = 0; t < 4; t++) ne[t] = nEl[(ct << 6) + t * 16 + m];
        v4f acc[4][2];
#pragma unroll
        for (int t = 0; t < 4; t++)
#pragma unroll
            for (int s = 0; s < 2; s++) acc[t][s] = (v4f){0.f, 0.f, 0.f, 0.f};
#pragma unroll
        for (int dc = 0; dc < 8; dc++) {       // 8 indep chains, B-reuse x2
#pragma unroll
            for (int t = 0; t < 4; t++) {
                v8s bf = S.B[cur][t * 512 + dc * 64 + g * 16 + m];
                acc[t][0] = __builtin_amdgcn_mfma_f32_16x16x32_bf16(a[0][dc], bf, acc[t][0], 0, 0, 0);
                acc[t][1] = __builtin_amdgcn_mfma_f32_16x16x32_bf16(a[1][dc], bf, acc[t][1], 0, 0, 0);
            }
        }
#pragma unroll
        for (int t = 0; t < 4; t++) {          // ascending code: tie -> low idx
            int code = (ct << 6) + t * 16 + m;
#pragma unroll
            for (int r = 0; r < 4; r++) {
                float s0 = ne[t] - acc[t][0][r];
                if (s0 < best[0][r]) { best[0][r] = s0; bidx[0][r] = code; }
                float s1 = ne[t] - acc[t][1][r];
                if (s1 < best[1][r]) { best[1][r] = s1; bidx[1][r] = code; }
            }
        }
    }

    // winner reduce over 16 code-columns
#pragma unroll
    for (int s = 0; s < 2; s++)
#pragma unroll
        for (int r = 0; r < 4; r++) {
            uint32_t sb = __float_as_uint(best[s][r]);
            sb = (sb & 0x80000000u) ? ~sb : (sb | 0x80000000u);
            unsigned long long pk = ((unsigned long long)sb << 32) | (uint32_t)bidx[s][r];
#pragma unroll
            for (int off = 1; off < 16; off <<= 1) {
                unsigned long long o = __shfl_xor(pk, off);
                if (o < pk) pk = o;
            }
            if (m == 0)                        // C/D row = g*4 + r
                idxLds[w * 32 + s * 16 + g * 4 + r] = (int)(pk & 0xffffffffu);
        }

    // epilogue: 4 halves of 32 rows; coalesced row gather -> Eg -> NCHW + loss
    float lsum = 0.f;
    const float* zb = z + ((size_t)b << 18);
    float* ob = out + ((size_t)b << 18);
    int jj = (tid & 7) << 2, dt = tid >> 3;    // output mapping
#pragma unroll 1
    for (int h = 0; h < 4; h++) {
        __syncthreads();                       // S free (B / prev Eg done)
#pragma unroll
        for (int i = 0; i < 8; i++) {          // row = w + 4i (wave-uniform)
            int row = w + (i << 2);
            int k = idxLds[(h << 5) + row];
            float4 v = ((const float4*)(E + ((size_t)k << 8)))[lane];
            *(float4*)&S.Eg[row * 260 + (lane << 2)] = v;   // bank-balanced
        }
        __syncthreads();
#pragma unroll
        for (int i = 0; i < 8; i++) {
            int d = dt + (i << 5);
            size_t o = (size_t)d * 1024 + hw0 + (h << 5) + jj;
            float4 zv = *(const float4*)(zb + o);
            float4 ev;
            ev.x = S.Eg[(jj + 0) * 260 + d]; ev.y = S.Eg[(jj + 1) * 260 + d];
            ev.z = S.Eg[(jj + 2) * 260 + d]; ev.w = S.Eg[(jj + 3) * 260 + d];
            *(float4*)(ob + o) = ev;           // z_st forward == z_quant
            float dx = ev.x - zv.x, dy = ev.y - zv.y;
            float dz2 = ev.z - zv.z, dw = ev.w - zv.w;
            lsum += dx * dx + dy * dy + dz2 * dz2 + dw * dw;
        }
    }
#pragma unroll
    for (int off = 1; off < 64; off <<= 1) lsum += __shfl_xor(lsum, off);
    if ((tid & 63) == 0) w4[w] = lsum;
    __syncthreads();
    if (tid == 0) atomicAdd(accum, w4[0] + w4[1] + w4[2] + w4[3]);
#undef STAGE
}

// ---- Kernel 4: scalar outputs ----------------------------------------------
__global__ void k_loss(const float* __restrict__ accum, float* __restrict__ out) {
    if (threadIdx.x == 0) {
        float s = accum[0] * (1.0f / 8388608.0f);
        out[8388608] = 1.25f * s;
        out[8388609] = s;
        out[8388610] = s;
    }
}

extern "C" void kernel_launch(void* const* d_in, const int* in_sizes, int n_in,
                              void* d_out, int out_size, void* d_ws, size_t ws_size,
                              hipStream_t stream) {
    const float* z = (const float*)d_in[0];
    const float* E = (const float*)d_in[1];
    char* ws = (char*)d_ws;
    unsigned short* Abf   = (unsigned short*)(ws);               // 16,777,216 B
    v8s*            Esw   = (v8s*)(ws + 16777216);               //    524,288 B
    float*          nE    = (float*)(ws + 17301504);             //      4,096 B
    float*          accum = (float*)(ws + 17305600);             //          4 B
    float* out = (float*)d_out;

    hipLaunchKernelGGL(k_prep_e, dim3(64),  dim3(256), 0, stream, E, Esw, nE, accum);
    hipLaunchKernelGGL(k_prep_a, dim3(512), dim3(512), 0, stream, z, Abf);
    hipLaunchKernelGGL(k_main,   dim3(256), dim3(256), 0, stream,
                       Abf, Esw, nE, z, E, out, accum);
    hipLaunchKernelGGL(k_loss,   dim3(1),   dim3(64),  0, stream, accum, out);
}

// Round 5
// 127.883 us; speedup vs baseline: 1.2555x; 1.0253x over previous
//
#include <hip/hip_runtime.h>
#include <hip/hip_bf16.h>
#include <stdint.h>

// VQ-VAE vector quantizer forward, MI355X (gfx950).
// z: [32,256,32,32] fp32 (NCHW), E: [1024,256] fp32.
// score(n,k) = 0.5*||e_k||^2 - <f_n,e_k>  (argmin-equivalent to d2)
// dots via bf16 MFMA 16x16x32 fp32-accum; losses/gather exact fp32.
//
// R5: k_main = 256 blocks x 512 thr (8 waves, 2/SIMD — R4 was 1/SIMD and
// issue-serialized ds_read vs MFMA). 128 rows/block, 16 rows/wave. B staged
// from pre-swizzled Esw via global_load_lds, 64-code chunks double-buffered.
// Epilogue uses an XOR-swizzled float4 LDS tile (uniform bank coverage both
// directions — R4's scalar reads were 8-lane/bank, 786k conflict cycles).

typedef short v8s __attribute__((ext_vector_type(8)));
typedef float v4f __attribute__((ext_vector_type(4)));

__device__ inline unsigned short f2bf(float f) {  // RNE fp32->bf16
    uint32_t u = __float_as_uint(f);
    return (unsigned short)((u + 0x7fffu + ((u >> 16) & 1u)) >> 16);
}

// ---- Kernel 1: z (NCHW fp32) -> Abf[n][d] bf16, register-only transpose ----
__global__ __launch_bounds__(512) void k_prep_a(const float* __restrict__ z,
                                                unsigned short* __restrict__ Abf) {
    int tid = threadIdx.x;
    int b = blockIdx.x >> 4, hw0 = (blockIdx.x & 15) << 6;
    int t15 = tid & 15, dblk = tid >> 4;            // hwq = 4*t15, d0 = 8*dblk
    const float* zp = z + ((size_t)b << 18) + (size_t)(dblk << 3) * 1024 + hw0 + (t15 << 2);
    float4 L[8];
#pragma unroll
    for (int j = 0; j < 8; j++)
        L[j] = *(const float4*)(zp + (size_t)j * 1024);
    const float* Lf = (const float*)L;
    v8s* Aout = (v8s*)Abf + ((size_t)(b * 1024 + hw0 + (t15 << 2))) * 32 + dblk;
#pragma unroll
    for (int c = 0; c < 4; c++) {
        union { v8s v; unsigned short s[8]; } u;
#pragma unroll
        for (int j = 0; j < 8; j++) u.s[j] = f2bf(Lf[j * 4 + c]);
        Aout[(size_t)c * 32] = u.v;
    }
}

// ---- Kernel 2: E -> SWIZZLED Ebf bf16 + nE + accum=0 -----------------------
// Unit for (k, dc, g): U = (k>>4)*512 + dc*64 + g*16 + (k&15),
// holding elems d = dc*32 + g*8 .. +8. Coalesced 16B stores.
__global__ __launch_bounds__(256) void k_prep_e(const float* __restrict__ E,
                                                v8s* __restrict__ Esw,
                                                float* __restrict__ nE,
                                                float* __restrict__ accum) {
    __shared__ float Ef[16][264];
    int q = blockIdx.x, tid = threadIdx.x;
    const float4* Ein = (const float4*)(E + ((size_t)q << 12));
#pragma unroll
    for (int i = 0; i < 4; i++) {
        int f4 = i * 256 + tid;
        int row = f4 >> 6, c4 = (f4 & 63) << 2;
        *(float4*)&Ef[row][c4] = Ein[f4];
    }
    __syncthreads();
    {
        int c = tid >> 4, l = tid & 15;
        float s = 0.f;
#pragma unroll
        for (int j = 0; j < 16; j++) { float v = Ef[c][l + 16 * j]; s += v * v; }
#pragma unroll
        for (int off = 1; off < 16; off <<= 1) s += __shfl_xor(s, off);
        if (l == 0) nE[q * 16 + c] = 0.5f * s;
    }
#pragma unroll
    for (int i = 0; i < 2; i++) {
        int u = tid + i * 256;
        int um = u & 15, ug = (u >> 4) & 3, udc = (u >> 6) & 7;
        int d0 = udc * 32 + ug * 8;
        union { v8s v; unsigned short s[8]; } pk;
#pragma unroll
        for (int e = 0; e < 8; e++) pk.s[e] = f2bf(Ef[um][d0 + e]);
        Esw[((size_t)q << 9) + u] = pk.v;
    }
    if (q == 0 && tid == 0) accum[0] = 0.f;
}

// ---- Kernel 3: fused GEMM+argmin+gather+output+loss -------------------------
__global__ __launch_bounds__(512) void k_main(
        const unsigned short* __restrict__ Abf,
        const v8s* __restrict__ Esw,
        const float* __restrict__ nE,
        const float* __restrict__ z,
        const float* __restrict__ E,
        float* __restrict__ out,
        float* __restrict__ accum) {
    __shared__ union {
        v8s    B[2][2048];          // 2 x 32 KB double-buffer
        float4 Eg4[2048];           // epilogue swizzled tile (32 KB)
    } S;
    __shared__ float nEl[1024];
    __shared__ int   idxLds[128];
    __shared__ float w8[8];

    int tid = threadIdx.x;
    int lane = tid & 63, w = tid >> 6;         // 8 waves
    int g = lane >> 4, m = lane & 15;          // MFMA lane coords
    int R0 = blockIdx.x << 7;                  // 128 rows/block
    int b = R0 >> 10;

#pragma unroll
    for (int i = 0; i < 2; i++) nEl[tid + i * 512] = nE[tid + i * 512];

    // A frags: 16 rows/wave, read once (L3-warm Abf)
    v8s a[8];
    {
        const v8s* Ap = (const v8s*)Abf;
        int row = R0 + w * 16 + m;
#pragma unroll
        for (int dc = 0; dc < 8; dc++)
            a[dc] = Ap[(size_t)row * 32 + dc * 4 + g];
    }

    // contiguous staging: chunk = 2048 v8s (32 KB); thread stages j*512+tid
#define STAGE(ch, buf)                                                        \
    {                                                                         \
        _Pragma("unroll")                                                     \
        for (int j = 0; j < 4; j++) {                                         \
            __builtin_amdgcn_global_load_lds(                                 \
                (const __attribute__((address_space(1))) void*)               \
                    (Esw + ((size_t)(ch) << 11) + (j << 9) + (w << 6) + lane),\
                (__attribute__((address_space(3))) void*)                     \
                    &S.B[buf][(j << 9) + (w << 6)],                           \
                16, 0, 0);                                                    \
        }                                                                     \
    }

    float best[4]; int bidx[4];
#pragma unroll
    for (int r = 0; r < 4; r++) { best[r] = 3.4e38f; bidx[r] = 0; }

    STAGE(0, 0);
#pragma unroll 1
    for (int ct = 0; ct < 16; ct++) {
        int cur = ct & 1;
        __syncthreads();                       // chunk ct resident
        if (ct < 15) STAGE(ct + 1, cur ^ 1);
        float ne[4];
#pragma unroll
        for (int t = 0; t < 4; t++) ne[t] = nEl[(ct << 6) + t * 16 + m];
        v4f acc[4];
#pragma unroll
        for (int t = 0; t < 4; t++) acc[t] = (v4f){0.f, 0.f, 0.f, 0.f};
#pragma unroll
        for (int dc = 0; dc < 8; dc++) {       // 4 indep chains/wave
#pragma unroll
            for (int t = 0; t < 4; t++) {
                v8s bf = S.B[cur][t * 512 + dc * 64 + g * 16 + m];
                acc[t] = __builtin_amdgcn_mfma_f32_16x16x32_bf16(a[dc], bf, acc[t], 0, 0, 0);
            }
        }
#pragma unroll
        for (int t = 0; t < 4; t++) {          // ascending code: tie -> low idx
            int code = (ct << 6) + t * 16 + m;
#pragma unroll
            for (int r = 0; r < 4; r++) {
                float s0 = ne[t] - acc[t][r];
                if (s0 < best[r]) { best[r] = s0; bidx[r] = code; }
            }
        }
    }

    // winner reduce over 16 code-columns (pack: min => low score, low idx)
#pragma unroll
    for (int r = 0; r < 4; r++) {
        uint32_t sb = __float_as_uint(best[r]);
        sb = (sb & 0x80000000u) ? ~sb : (sb | 0x80000000u);
        unsigned long long pk = ((unsigned long long)sb << 32) | (uint32_t)bidx[r];
#pragma unroll
        for (int off = 1; off < 16; off <<= 1) {
            unsigned long long o = __shfl_xor(pk, off);
            if (o < pk) pk = o;
        }
        if (m == 0)                            // C/D row = g*4 + r
            idxLds[w * 16 + g * 4 + r] = (int)(pk & 0xffffffffu);
    }
    __syncthreads();                           // winners visible; B free

    // epilogue: 4 phases of 32 rows through XOR-swizzled float4 tile.
    // cell (hw, dq) at slot hw*64 + (dq ^ hw): row writes = contiguous 1KB
    // permutation (uniform banks); reads = b128, group dq0^(lane&7) uniform.
    float lsum = 0.f;
    const float* zb = z + ((size_t)b << 18);
    float* ob = out + ((size_t)b << 18);
    int hwl = tid & 31, dq0 = tid >> 5;        // dq0: 0..15
#pragma unroll 1
    for (int ph = 0; ph < 4; ph++) {
#pragma unroll
        for (int i = 0; i < 4; i++) {          // rows w + 8i (wave-uniform)
            int row = w + (i << 3);
            int k = idxLds[(ph << 5) + row];
            float4 v = ((const float4*)(E + ((size_t)k << 8)))[lane];
            S.Eg4[(row << 6) + (lane ^ row)] = v;
        }
        __syncthreads();
        int hwp = (R0 & 1023) + (ph << 5) + hwl;
#pragma unroll
        for (int i = 0; i < 4; i++) {
            int dq = dq0 + (i << 4);
            float4 ev = S.Eg4[(hwl << 6) + (dq ^ hwl)];
            size_t o = ((size_t)dq << 12) + hwp;        // (4*dq)*1024 + hwp
            float z0 = zb[o], z1 = zb[o + 1024], z2 = zb[o + 2048], z3 = zb[o + 3072];
            ob[o] = ev.x; ob[o + 1024] = ev.y; ob[o + 2048] = ev.z; ob[o + 3072] = ev.w;
            float dx = ev.x - z0, dy = ev.y - z1, dz2 = ev.z - z2, dw = ev.w - z3;
            lsum += dx * dx + dy * dy + dz2 * dz2 + dw * dw;
        }
        __syncthreads();                        // tile reused next phase
    }
#pragma unroll
    for (int off = 1; off < 64; off <<= 1) lsum += __shfl_xor(lsum, off);
    if (lane == 0) w8[w] = lsum;
    __syncthreads();
    if (tid == 0) {
        float s = 0.f;
#pragma unroll
        for (int i = 0; i < 8; i++) s += w8[i];
        atomicAdd(accum, s);
    }
#undef STAGE
}

// ---- Kernel 4: scalar outputs ----------------------------------------------
__global__ void k_loss(const float* __restrict__ accum, float* __restrict__ out) {
    if (threadIdx.x == 0) {
        float s = accum[0] * (1.0f / 8388608.0f);
        out[8388608] = 1.25f * s;
        out[8388609] = s;
        out[8388610] = s;
    }
}

extern "C" void kernel_launch(void* const* d_in, const int* in_sizes, int n_in,
                              void* d_out, int out_size, void* d_ws, size_t ws_size,
                              hipStream_t stream) {
    const float* z = (const float*)d_in[0];
    const float* E = (const float*)d_in[1];
    char* ws = (char*)d_ws;
    unsigned short* Abf   = (unsigned short*)(ws);               // 16,777,216 B
    v8s*            Esw   = (v8s*)(ws + 16777216);               //    524,288 B
    float*          nE    = (float*)(ws + 17301504);             //      4,096 B
    float*          accum = (float*)(ws + 17305600);             //          4 B
    float* out = (float*)d_out;

    hipLaunchKernelGGL(k_prep_e, dim3(64),  dim3(256), 0, stream, E, Esw, nE, accum);
    hipLaunchKernelGGL(k_prep_a, dim3(512), dim3(512), 0, stream, z, Abf);
    hipLaunchKernelGGL(k_main,   dim3(256), dim3(512), 0, stream,
                       Abf, Esw, nE, z, E, out, accum);
    hipLaunchKernelGGL(k_loss,   dim3(1),   dim3(64),  0, stream, accum, out);
}